// Round 13
// baseline (778.434 us; speedup 1.0000x reference)
//
#include <hip/hip_runtime.h>
#include <hip/hip_bf16.h>
#include <cstdio>
#include <cstdint>

#define BB 8
#define NN 4096
#define FF 64

typedef __attribute__((ext_vector_type(8))) short bf16x8;
typedef __attribute__((ext_vector_type(4))) float f32x4;

__device__ __forceinline__ unsigned short f2bf(float f){
  unsigned int u = __float_as_uint(f);
  u += 0x7FFFu + ((u >> 16) & 1u);           // round-to-nearest-even
  return (unsigned short)(u >> 16);
}

__device__ __forceinline__ float leaky01(float x){ return x > 0.f ? x : 0.01f * x; }

// ================= layouts =================
// A staging image (BM=128): At[bid][t(64)][(r*8+g)*8+j] =
//   bf16(adj[b][m0 + r][t*64 + ((g^(r&7))<<3) + j]),  r in 0..127, bid = b + 8*mt, m0 = mt*128.
//   One contiguous 1 MB stream per block; tile t = 16 KB staged by 2 global_load_lds/thread (512 thr).
// B fragment order (R9-proven): Bt[b][ct(8)][t(64)][kk(2)][l(64)][j(8)]
//   element = scale * H[row = t*64 + kk*32 + (l>>4)*8 + j][col = ct*16 + (l&15)]
//   ct 0..3 = gcn half (cols 0..63), ct 4..7 = scat half.
//   Per (ct,t): 2 KB contiguous -> B also stages via global_load_lds (linear dest).

// ---------------- pass 0: fp32 adj -> A staging image + row sums ----------------
__global__ __launch_bounds__(256) void k_convert(const float* __restrict__ adj,
    unsigned short* __restrict__ At, float* __restrict__ dinv, float* __restrict__ dsq)
{
  const int bid = blockIdx.x;              // 256 blocks; b = bid&7 (XCD-aligned)
  const int b = bid & 7, mt = bid >> 3, m0 = mt * 128;
  const int tid = threadIdx.x;
  const int r = tid >> 3, g = tid & 7;     // r in 0..31; rows r+q*32, q=0..3
  const float* src[4];
  unsigned short* dst[4];
  float s[4];
  #pragma unroll
  for (int q = 0; q < 4; ++q){
    const int row = r + q * 32;            // row&7 == r&7
    src[q] = adj + ((size_t)b * NN + m0 + row) * NN + ((g ^ (r & 7)) << 3);
    dst[q] = At + (size_t)bid * 524288 + ((row * 8 + g) << 3);
    s[q] = 0.f;
  }
  for (int t = 0; t < 64; ++t){
    #pragma unroll
    for (int q = 0; q < 4; ++q){
      const float* p = src[q] + t * 64;
      float4 a = *(const float4*)p, c = *(const float4*)(p + 4);
      s[q] += ((a.x + a.y) + (a.z + a.w)) + ((c.x + c.y) + (c.z + c.w));
      bf16x8 v;
      v[0]=(short)f2bf(a.x); v[1]=(short)f2bf(a.y); v[2]=(short)f2bf(a.z); v[3]=(short)f2bf(a.w);
      v[4]=(short)f2bf(c.x); v[5]=(short)f2bf(c.y); v[6]=(short)f2bf(c.z); v[7]=(short)f2bf(c.w);
      *(bf16x8*)(dst[q] + (size_t)t * 8192) = v;
    }
  }
  #pragma unroll
  for (int q = 0; q < 4; ++q){
    float sv = s[q];
    sv += __shfl_xor(sv, 1); sv += __shfl_xor(sv, 2); sv += __shfl_xor(sv, 4);
    if (g == 0){
      const int row = m0 + r + q * 32;
      dinv[(size_t)b * NN + row] = 1.0f / sv;
      dsq [(size_t)b * NN + row] = 1.0f / sqrtf(sv + 1.0f);
    }
  }
}

// ---------------- initial RHS in fragment order: ct0-3 = dsq*X, ct4-7 = dinv*X ----------
__global__ __launch_bounds__(256) void k_prep(const float* __restrict__ X,
    const float* __restrict__ dinv, const float* __restrict__ dsq,
    unsigned short* __restrict__ Bt)
{
  const int b = blockIdx.y, n0 = blockIdx.x * 64, tid = threadIdx.x;
  __shared__ unsigned short tg[64][68], ts[64][68];
  #pragma unroll
  for (int i = 0; i < 4; ++i){
    int idx = i * 256 + tid, n = idx >> 4, c4 = (idx & 15) * 4;
    size_t rb = (size_t)b * NN + n0 + n;
    float4 x = *(const float4*)(X + rb * 64 + c4);
    float di = dinv[b * NN + n0 + n], dv = dsq[b * NN + n0 + n];
    tg[c4 + 0][n] = f2bf(dv * x.x); tg[c4 + 1][n] = f2bf(dv * x.y);
    tg[c4 + 2][n] = f2bf(dv * x.z); tg[c4 + 3][n] = f2bf(dv * x.w);
    ts[c4 + 0][n] = f2bf(di * x.x); ts[c4 + 1][n] = f2bf(di * x.y);
    ts[c4 + 2][n] = f2bf(di * x.z); ts[c4 + 3][n] = f2bf(di * x.w);
  }
  __syncthreads();
  const int t = n0 >> 6;
  #pragma unroll
  for (int it = 0; it < 8; ++it){
    int idx = it * 256 + tid;
    int half = idx & 1, l = (idx >> 1) & 63, kk = (idx >> 7) & 1, ct = (idx >> 8) & 7;
    int cl = ((ct & 3) << 4) + (l & 15);
    int nl = kk * 32 + ((l >> 4) << 3) + half * 4;
    ushort4 v = (ct < 4) ? *(const ushort4*)&tg[cl][nl] : *(const ushort4*)&ts[cl][nl];
    *(ushort4*)(Bt + ((((size_t)b * 8 + ct) * 64 + t) * 2 + kk) * 512 + (l << 3) + half * 4) = v;
  }
}

// ---- fused GEMM + epilogue: BM=128, 512 thr, A+B staged via 4-deep LDS pipeline ----
template<int NC>
__global__ __launch_bounds__(512, 1) void k_gemm_fused(
    const unsigned short* __restrict__ At,
    const unsigned short* __restrict__ BtR, int ct0,
    const float* __restrict__ sprev, float* __restrict__ P, float* __restrict__ snap,
    const float* __restrict__ dinv, int writeVtS,
    const float* __restrict__ gprev, float* __restrict__ gout,
    const float* __restrict__ dsq, int writeVtG,
    unsigned short* __restrict__ BtW)
{
  constexpr int NF = NC / 64;
  __shared__ __align__(16) unsigned short As[4][128 * 64];        // 64 KB
  __shared__ __align__(16) unsigned short Bs[4][NF * 4 * 1024];   // 32 / 64 KB
  const int bid = blockIdx.x;                                      // 256 blocks
  const int b = bid & 7, mt = bid >> 3, m0 = mt * 128;
  const int tid = threadIdx.x;
  const int w = tid >> 6, l = tid & 63;
  const int wh = w >> 2, wc = w & 3;
  const int r0 = l & 15, hq = l >> 4, sw = r0 & 7;
  const unsigned short* Atile = At + (size_t)bid * 524288;

  auto stageA = [&](int buf, int t){
    #pragma unroll
    for (int i = 0; i < 2; ++i){
      const int idx = i * 512 + tid;
      const unsigned short* gp = Atile + (size_t)t * 8192 + (idx << 3);
      __builtin_amdgcn_global_load_lds((const __attribute__((address_space(1))) void*)gp,
          (__attribute__((address_space(3))) void*)(&As[buf][idx << 3]), 16, 0, 0);
    }
  };
  auto stageB = [&](int buf, int t){
    #pragma unroll
    for (int i = 0; i < NF; ++i){
      const int idx = i * 512 + tid;
      const int ctl = idx >> 7, e = (idx & 127) << 3;
      const unsigned short* gp = BtR + (((size_t)b * 8 + ct0 + ctl) * 64 + t) * 1024 + e;
      __builtin_amdgcn_global_load_lds((const __attribute__((address_space(1))) void*)gp,
          (__attribute__((address_space(3))) void*)(&Bs[buf][idx << 3]), 16, 0, 0);
    }
  };

  f32x4 acc[4][NF];
  #pragma unroll
  for (int mi = 0; mi < 4; ++mi)
    #pragma unroll
    for (int ni = 0; ni < NF; ++ni)
      #pragma unroll
      for (int j = 0; j < 4; ++j) acc[mi][ni][j] = 0.f;

  auto CMP = [&](int ib){
    const unsigned short* asb = &As[ib][0];
    const unsigned short* bsb = &Bs[ib][0];
    #pragma unroll
    for (int kk = 0; kk < 2; ++kk){
      const int g8 = ((kk * 4 + hq) ^ sw) << 3;
      bf16x8 pb[NF];
      #pragma unroll
      for (int ni = 0; ni < NF; ++ni)
        pb[ni] = *(const bf16x8*)&bsb[(wc * NF + ni) * 1024 + kk * 512 + (l << 3)];
      #pragma unroll
      for (int mi = 0; mi < 4; ++mi){
        bf16x8 af = *(const bf16x8*)&asb[(wh * 64 + mi * 16 + r0) * 64 + g8];
        #pragma unroll
        for (int ni = 0; ni < NF; ++ni)
          acc[mi][ni] = __builtin_amdgcn_mfma_f32_16x16x32_bf16(af, pb[ni], acc[mi][ni], 0, 0, 0);
      }
    }
  };

  #define VMW(N) asm volatile("s_waitcnt vmcnt(" #N ")" ::: "memory")
  #define BARX do{ __builtin_amdgcn_s_barrier(); asm volatile("" ::: "memory"); }while(0)
  // SUB(T): issue stage(T+2) -> counted wait (retires this wave's stage(T)) -> barrier -> CMP(T).
  // Buffer (T+2)&3 was last read in CMP(T-2), which precedes barrier(T-1): 1-barrier separation.
  #define SUB(T, N) do{ \
    if ((T) + 2 < 64){ stageA(((T)+2)&3, (T)+2); stageB(((T)+2)&3, (T)+2); } \
    VMW(N); BARX; CMP((T)&3); asm volatile("" ::: "memory"); }while(0)

  stageA(0, 0); stageB(0, 0); stageA(1, 1); stageB(1, 1);
  if constexpr (NC == 64){        // 3 vmem ops per stage -> steady vmcnt(6)
    SUB(0, 6);
    #pragma unroll 1
    for (int t = 1; t < 62; ++t) SUB(t, 6);
    SUB(62, 3); SUB(63, 0);
  } else {                        // 4 vmem ops per stage -> steady vmcnt(8)
    SUB(0, 8);
    #pragma unroll 1
    for (int t = 1; t < 62; ++t) SUB(t, 8);
    SUB(62, 4); SUB(63, 0);
  }
  #undef SUB

  // ---- fused epilogue: C/D layout col = lane&15 (r0), row = hq*4 + j ----
  const bool isScat = (NC == 64) || (wc >= 2);
  if (isScat){
    #pragma unroll
    for (int mi = 0; mi < 4; ++mi){
      const int rb = m0 + wh * 64 + mi * 16 + hq * 4;
      const size_t rowb = (size_t)b * NN + rb;
      float4 dv4 = *(const float4*)(dinv + (size_t)b * NN + rb);
      #pragma unroll
      for (int ni = 0; ni < NF; ++ni){
        const int cs = (NC == 64) ? (wc * 16 + r0) : ((wc - 2) * 32 + ni * 16 + r0);
        float pn[4];
        #pragma unroll
        for (int j = 0; j < 4; ++j){
          float pv = sprev[(rowb + j) * 64 + cs];
          pn[j] = 0.5f * (pv + acc[mi][ni][j]);
          P[(rowb + j) * 64 + cs] = pn[j];
        }
        if (snap){
          #pragma unroll
          for (int j = 0; j < 4; ++j) snap[(rowb + j) * 64 + cs] = pn[j];
        }
        if (writeVtS){
          const int ct = (NC == 64) ? (4 + wc) : (4 + (wc - 2) * 2 + ni);
          const int tp = rb >> 6, kkp = (rb >> 5) & 1;
          const int lp = r0 + 16 * ((rb >> 3) & 3), hf = (rb >> 2) & 1;
          ushort4 vv = make_ushort4(f2bf(dv4.x * pn[0]), f2bf(dv4.y * pn[1]),
                                    f2bf(dv4.z * pn[2]), f2bf(dv4.w * pn[3]));
          *(ushort4*)(BtW + ((((size_t)b * 8 + ct) * 64 + tp) * 2 + kkp) * 512
                          + (lp << 3) + hf * 4) = vv;
        }
      }
    }
  }
  if constexpr (NC == 128){
    if (!isScat){                                     // gcn waves: wc < 2
      #pragma unroll
      for (int mi = 0; mi < 4; ++mi){
        const int rb = m0 + wh * 64 + mi * 16 + hq * 4;
        const size_t rowb = (size_t)b * NN + rb;
        float4 dq4 = *(const float4*)(dsq + (size_t)b * NN + rb);
        #pragma unroll
        for (int ni = 0; ni < NF; ++ni){
          const int cg = wc * 32 + ni * 16 + r0;      // gcn col 0..63
          float hn[4];
          const float dq[4] = {dq4.x, dq4.y, dq4.z, dq4.w};
          #pragma unroll
          for (int j = 0; j < 4; ++j){
            float hv = gprev[(rowb + j) * 64 + cg];
            hn[j] = (acc[mi][ni][j] + dq[j] * hv) * dq[j];
            gout[(rowb + j) * 64 + cg] = hn[j];
          }
          if (writeVtG){
            const int ct = wc * 2 + ni;
            const int tp = rb >> 6, kkp = (rb >> 5) & 1;
            const int lp = r0 + 16 * ((rb >> 3) & 3), hf = (rb >> 2) & 1;
            ushort4 vv = make_ushort4(f2bf(dq[0] * hn[0]), f2bf(dq[1] * hn[1]),
                                      f2bf(dq[2] * hn[2]), f2bf(dq[3] * hn[3]));
            *(ushort4*)(BtW + ((((size_t)b * 8 + ct) * 64 + tp) * 2 + kkp) * 512
                            + (lp << 3) + hf * 4) = vv;
          }
        }
      }
    }
  }
}

// ---------------- attention over 6 branches + 2-layer MLP ----------------
__global__ __launch_bounds__(256) void k_attn(
    const float* __restrict__ X,  const float* __restrict__ hA, const float* __restrict__ hA2,
    const float* __restrict__ U1, const float* __restrict__ U2, const float* __restrict__ U4,
    const float* __restrict__ U8, const float* __restrict__ W1, const float* __restrict__ b1,
    const float* __restrict__ W2, const float* __restrict__ b2, const float* __restrict__ av,
    const int* __restrict__ momp, float* __restrict__ out)
{
  __shared__ float W1s[64][65], W2s[64][65];
  __shared__ float a1s[64], a2s[64], b1s[64], b2s[64];
  __shared__ float hp[4][64], o1[4][64];
  const int tid = threadIdx.x;
  for (int e = tid; e < 4096; e += 256){
    W1s[e >> 6][e & 63] = W1[e];
    W2s[e >> 6][e & 63] = W2[e];
  }
  if (tid < 64){ a1s[tid] = av[tid]; a2s[tid] = av[64 + tid]; b1s[tid] = b1[tid]; b2s[tid] = b2[tid]; }
  __syncthreads();
  const int w = tid >> 6, l = tid & 63;
  size_t row = (size_t)blockIdx.x * 4 + w;
  size_t off = row * 64 + l;
  float x  = X[off];
  float u1 = U1[off], u2 = U2[off], u4 = U4[off], u8 = U8[off];
  float br[6];
  br[0] = leaky01(hA[off]);
  br[1] = leaky01(hA2[off]);
  float d1 = fabsf(x - u1), d2 = fabsf(u1 - u2), d3 = fabsf(u2 - u4), d4 = fabsf(u4 - u8);
  int mom = *momp;
  if (mom == 1){ br[2] = d1; br[3] = d2; br[4] = d3; br[5] = d4; }
  else {
    float m = (float)mom;
    br[2] = powf(d1, m); br[3] = powf(d2, m); br[4] = powf(d3, m); br[5] = powf(d4, m);
  }
  float v = fmaxf(x, 0.f) * a1s[l];
  for (int o = 32; o; o >>= 1) v += __shfl_xor(v, o);
  float base = v;
  float e[6];
  #pragma unroll
  for (int k = 0; k < 6; ++k){
    float t = fmaxf(br[k], 0.f) * a2s[l];
    for (int o = 32; o; o >>= 1) t += __shfl_xor(t, o);
    e[k] = base + t;
  }
  float mx = e[0];
  #pragma unroll
  for (int k = 1; k < 6; ++k) mx = fmaxf(mx, e[k]);
  float s = 0.f, att[6];
  #pragma unroll
  for (int k = 0; k < 6; ++k){ att[k] = expf(e[k] - mx); s += att[k]; }
  float inv = 1.0f / (6.0f * s);
  float hpv = 0.f;
  #pragma unroll
  for (int k = 0; k < 6; ++k) hpv += att[k] * br[k];
  hpv *= inv;
  hp[w][l] = hpv;
  __syncthreads();
  float acc = b1s[l];
  #pragma unroll 8
  for (int c = 0; c < 64; ++c) acc += hp[w][c] * W1s[l][c];
  o1[w][l] = leaky01(acc);
  __syncthreads();
  float acc2 = b2s[l];
  #pragma unroll 8
  for (int c = 0; c < 64; ++c) acc2 += o1[w][c] * W2s[l][c];
  out[off] = leaky01(acc2);
}

// ---------------- workspace layout ----------------
static constexpr size_t OFF_ADJB = 0;                                   // bf16 A staging image
static constexpr size_t OFF_VTA  = OFF_ADJB + (size_t)BB * NN * NN * 2; // bf16 frag-order B
static constexpr size_t OFF_VTB  = OFF_VTA  + (size_t)BB * 128 * NN * 2;
static constexpr size_t OFF_HA   = OFF_VTB  + (size_t)BB * 128 * NN * 2;
static constexpr size_t OFF_HA2  = OFF_HA   + (size_t)BB * NN * 64 * 4;
static constexpr size_t OFF_P    = OFF_HA2  + (size_t)BB * NN * 64 * 4;
static constexpr size_t OFF_U1   = OFF_P    + (size_t)BB * NN * 64 * 4;
static constexpr size_t OFF_U2   = OFF_U1   + (size_t)BB * NN * 64 * 4;
static constexpr size_t OFF_U4   = OFF_U2   + (size_t)BB * NN * 64 * 4;
static constexpr size_t OFF_U8   = OFF_U4   + (size_t)BB * NN * 64 * 4;
static constexpr size_t OFF_DINV = OFF_U8   + (size_t)BB * NN * 64 * 4;
static constexpr size_t OFF_DS   = OFF_DINV + (size_t)BB * NN * 4;
static constexpr size_t WS_NEED  = OFF_DS   + (size_t)BB * NN * 4;

extern "C" void kernel_launch(void* const* d_in, const int* in_sizes, int n_in,
                              void* d_out, int out_size, void* d_ws, size_t ws_size,
                              hipStream_t stream)
{
  const float* X   = (const float*)d_in[0];
  const float* adj = (const float*)d_in[1];
  const float* W1  = (const float*)d_in[2];
  const float* b1  = (const float*)d_in[3];
  const float* W2  = (const float*)d_in[4];
  const float* b2  = (const float*)d_in[5];
  const float* av  = (const float*)d_in[6];
  const int*  momp = (const int*)d_in[7];
  float* out = (float*)d_out;

  if (ws_size < WS_NEED){
    fprintf(stderr, "kernel_launch: workspace too small: %zu < %zu\n", ws_size, WS_NEED);
    return;
  }
  char* w = (char*)d_ws;
  unsigned short* At  = (unsigned short*)(w + OFF_ADJB);
  unsigned short* vtA = (unsigned short*)(w + OFF_VTA);
  unsigned short* vtB = (unsigned short*)(w + OFF_VTB);
  float* hA   = (float*)(w + OFF_HA);
  float* hA2  = (float*)(w + OFF_HA2);
  float* P    = (float*)(w + OFF_P);
  float* U1   = (float*)(w + OFF_U1);
  float* U2   = (float*)(w + OFF_U2);
  float* U4   = (float*)(w + OFF_U4);
  float* U8   = (float*)(w + OFF_U8);
  float* dinv = (float*)(w + OFF_DINV);
  float* dsq  = (float*)(w + OFF_DS);

  k_convert<<<256, 256, 0, stream>>>(adj, At, dinv, dsq);
  dim3 tg64(NN / 64, BB);
  k_prep<<<tg64, 256, 0, stream>>>(X, dinv, dsq, vtA);

  // pass 1: dual RHS (gcn: dsq*X -> hA, scat: dinv*X -> P,U1); writes vtB (both halves)
  k_gemm_fused<128><<<256, 512, 0, stream>>>(At, vtA, 0,
      X, P, U1, dinv, 1, X, hA, dsq, 1, vtB);
  // pass 2: dual RHS (gcn -> hA2, scat -> P,U2); writes vtA (scat half)
  k_gemm_fused<128><<<256, 512, 0, stream>>>(At, vtB, 0,
      P, P, U2, dinv, 1, hA, hA2, dsq, 0, vtA);
  // passes 3..8: scattering only, alternate vtA/vtB
  unsigned short* vr = vtA;
  unsigned short* vw = vtB;
  for (int k = 3; k <= 8; ++k){
    float* snap = (k == 4) ? U4 : nullptr;
    float* pdst = (k == 8) ? U8 : P;
    k_gemm_fused<64><<<256, 512, 0, stream>>>(At, vr, 4,
        P, pdst, snap, dinv, (k < 8) ? 1 : 0, nullptr, nullptr, nullptr, 0, vw);
    unsigned short* t = vr; vr = vw; vw = t;
  }

  k_attn<<<BB * NN / 4, 256, 0, stream>>>(X, hA, hA2, U1, U2, U4, U8,
                                          W1, b1, W2, b2, av, momp, out);
}

// Round 14
// 691.288 us; speedup vs baseline: 1.1261x; 1.1261x over previous
//
#include <hip/hip_runtime.h>
#include <hip/hip_bf16.h>
#include <cstdio>
#include <cstdint>

#define BB 8
#define NN 4096
#define FF 64

typedef __attribute__((ext_vector_type(8))) short bf16x8;
typedef __attribute__((ext_vector_type(4))) float f32x4;

__device__ __forceinline__ unsigned short f2bf(float f){
  unsigned int u = __float_as_uint(f);
  u += 0x7FFFu + ((u >> 16) & 1u);           // round-to-nearest-even
  return (unsigned short)(u >> 16);
}

__device__ __forceinline__ float leaky01(float x){ return x > 0.f ? x : 0.01f * x; }

// ================= layouts (R12-proven) =================
// A staging image (BM=64): At[bid][t(64)][(r*8+g)*8+j] =
//   bf16(adj[b][m0 + r][t*64 + ((g^(r&7))<<3) + j]),  r in 0..63, bid = b + 8*mt, m0 = mt*64.
// B fragment order: Bt[b][ct(8)][t(64)][kk(2)][l(64)][j(8)]
//   element = scale * H[row = t*64 + kk*32 + (l>>4)*8 + j][col = ct*16 + (l&15)]
//   ct 0..3 = gcn half (cols 0..63), ct 4..7 = scat half

// ---------------- pass 0: fp32 adj -> A staging image + row sums (R12 verbatim) --------
__global__ __launch_bounds__(256) void k_convert(const float* __restrict__ adj,
    unsigned short* __restrict__ At, float* __restrict__ dinv, float* __restrict__ dsq)
{
  const int bid = blockIdx.x;              // 512 blocks; b = bid&7 (XCD-aligned)
  const int b = bid & 7, mt = bid >> 3, m0 = mt * 64;
  const int tid = threadIdx.x;
  const int r = tid >> 3, g = tid & 7;     // r in 0..31; rows r and r+32 per thread
  const float* src0 = adj + ((size_t)b * NN + m0 + r) * NN + ((g ^ (r & 7)) << 3);
  const float* src1 = src0 + (size_t)32 * NN;            // (r+32)&7 == r&7
  unsigned short* dst0 = At + (size_t)bid * 262144 + (((r)      * 8 + g) << 3);
  unsigned short* dst1 = At + (size_t)bid * 262144 + (((r + 32) * 8 + g) << 3);
  float s0 = 0.f, s1 = 0.f;
  for (int t = 0; t < 64; ++t){
    const float* p0 = src0 + t * 64;
    float4 a = *(const float4*)p0, c = *(const float4*)(p0 + 4);
    s0 += ((a.x + a.y) + (a.z + a.w)) + ((c.x + c.y) + (c.z + c.w));
    bf16x8 v;
    v[0]=(short)f2bf(a.x); v[1]=(short)f2bf(a.y); v[2]=(short)f2bf(a.z); v[3]=(short)f2bf(a.w);
    v[4]=(short)f2bf(c.x); v[5]=(short)f2bf(c.y); v[6]=(short)f2bf(c.z); v[7]=(short)f2bf(c.w);
    *(bf16x8*)(dst0 + (size_t)t * 4096) = v;
    const float* p1 = src1 + t * 64;
    float4 e = *(const float4*)p1, h = *(const float4*)(p1 + 4);
    s1 += ((e.x + e.y) + (e.z + e.w)) + ((h.x + h.y) + (h.z + h.w));
    bf16x8 u;
    u[0]=(short)f2bf(e.x); u[1]=(short)f2bf(e.y); u[2]=(short)f2bf(e.z); u[3]=(short)f2bf(e.w);
    u[4]=(short)f2bf(h.x); u[5]=(short)f2bf(h.y); u[6]=(short)f2bf(h.z); u[7]=(short)f2bf(h.w);
    *(bf16x8*)(dst1 + (size_t)t * 4096) = u;
  }
  s0 += __shfl_xor(s0, 1); s0 += __shfl_xor(s0, 2); s0 += __shfl_xor(s0, 4);
  s1 += __shfl_xor(s1, 1); s1 += __shfl_xor(s1, 2); s1 += __shfl_xor(s1, 4);
  if (g == 0){
    dinv[(size_t)b * NN + m0 + r] = 1.0f / s0;
    dsq [(size_t)b * NN + m0 + r] = 1.0f / sqrtf(s0 + 1.0f);
    dinv[(size_t)b * NN + m0 + 32 + r] = 1.0f / s1;
    dsq [(size_t)b * NN + m0 + 32 + r] = 1.0f / sqrtf(s1 + 1.0f);
  }
}

// ---------------- initial RHS in fragment order: ct0-3 = dsq*X, ct4-7 = dinv*X ----------
__global__ __launch_bounds__(256) void k_prep(const float* __restrict__ X,
    const float* __restrict__ dinv, const float* __restrict__ dsq,
    unsigned short* __restrict__ Bt)
{
  const int b = blockIdx.y, n0 = blockIdx.x * 64, tid = threadIdx.x;
  __shared__ unsigned short tg[64][68], ts[64][68];
  #pragma unroll
  for (int i = 0; i < 4; ++i){
    int idx = i * 256 + tid, n = idx >> 4, c4 = (idx & 15) * 4;
    size_t rb = (size_t)b * NN + n0 + n;
    float4 x = *(const float4*)(X + rb * 64 + c4);
    float di = dinv[b * NN + n0 + n], dv = dsq[b * NN + n0 + n];
    tg[c4 + 0][n] = f2bf(dv * x.x); tg[c4 + 1][n] = f2bf(dv * x.y);
    tg[c4 + 2][n] = f2bf(dv * x.z); tg[c4 + 3][n] = f2bf(dv * x.w);
    ts[c4 + 0][n] = f2bf(di * x.x); ts[c4 + 1][n] = f2bf(di * x.y);
    ts[c4 + 2][n] = f2bf(di * x.z); ts[c4 + 3][n] = f2bf(di * x.w);
  }
  __syncthreads();
  const int t = n0 >> 6;
  #pragma unroll
  for (int it = 0; it < 8; ++it){
    int idx = it * 256 + tid;
    int half = idx & 1, l = (idx >> 1) & 63, kk = (idx >> 7) & 1, ct = (idx >> 8) & 7;
    int cl = ((ct & 3) << 4) + (l & 15);
    int nl = kk * 32 + ((l >> 4) << 3) + half * 4;
    ushort4 v = (ct < 4) ? *(const ushort4*)&tg[cl][nl] : *(const ushort4*)&ts[cl][nl];
    *(ushort4*)(Bt + ((((size_t)b * 8 + ct) * 64 + t) * 2 + kk) * 512 + (l << 3) + half * 4) = v;
  }
}

// ---- fused GEMM + epilogue: BM=64 (R12); NC==64 uses BK=128 super-steps ----
template<int NC>
__global__ __launch_bounds__(256, 2) void k_gemm_fused(
    const unsigned short* __restrict__ At,
    const unsigned short* __restrict__ BtR, int ct0,
    const float* __restrict__ sprev, float* __restrict__ P, float* __restrict__ snap,
    const float* __restrict__ dinv, int writeVtS,
    const float* __restrict__ gprev, float* __restrict__ gout,
    const float* __restrict__ dsq, int writeVtG,
    unsigned short* __restrict__ BtW)
{
  constexpr int NF = NC / 64;
  constexpr int AD = (NC == 64) ? 8 : 4;
  __shared__ __align__(16) unsigned short As[AD][64 * 64];   // 64 / 32 KB
  const int bid = blockIdx.x;                                 // 512 blocks
  const int b = bid & 7, mt = bid >> 3, m0 = mt * 64;
  const int tid = threadIdx.x;
  const int w = tid >> 6, l = tid & 63;
  const int r0 = l & 15, hq = l >> 4, sw = r0 & 7;
  const unsigned short* Atile = At + (size_t)bid * 262144;
  const unsigned short* Bb0 = BtR + (((size_t)b * 8 + ct0 + w * NF) * 64) * 1024 + (l << 3);
  const unsigned short* Bb1 = Bb0 + (size_t)64 * 1024;        // ni=1 (NC==128 only)

  auto stageA = [&](int buf, int t){
    const unsigned short* gp0 = Atile + (size_t)t * 4096 + (tid << 3);
    __builtin_amdgcn_global_load_lds((const __attribute__((address_space(1))) void*)gp0,
        (__attribute__((address_space(3))) void*)(&As[buf][tid << 3]), 16, 0, 0);
    __builtin_amdgcn_global_load_lds((const __attribute__((address_space(1))) void*)(gp0 + 2048),
        (__attribute__((address_space(3))) void*)(&As[buf][(256 + tid) << 3]), 16, 0, 0);
  };

  f32x4 acc[4][NF];
  #pragma unroll
  for (int mi = 0; mi < 4; ++mi)
    #pragma unroll
    for (int ni = 0; ni < NF; ++ni)
      #pragma unroll
      for (int j = 0; j < 4; ++j) acc[mi][ni][j] = 0.f;

  #define VMW(N) asm volatile("s_waitcnt vmcnt(" #N ")" ::: "memory")
  #define BARX do{ __builtin_amdgcn_s_barrier(); asm volatile("" ::: "memory"); }while(0)

  if constexpr (NC == 64){
    // ---- BK=128 super-steps: 2 k-tiles per barrier, 8 LDS tile-buffers ----
    bf16x8 bA[4], bB[4];
    auto LDBX = [&](bf16x8 (&PB)[4], int t2){          // B tiles t2, t2+1 (4 loads)
      PB[0] = *(const bf16x8*)(Bb0 + (size_t)t2 * 1024);
      PB[1] = *(const bf16x8*)(Bb0 + (size_t)t2 * 1024 + 512);
      PB[2] = *(const bf16x8*)(Bb0 + (size_t)(t2 + 1) * 1024);
      PB[3] = *(const bf16x8*)(Bb0 + (size_t)(t2 + 1) * 1024 + 512);
    };
    auto CMPT = [&](int ib, bf16x8 pb0, bf16x8 pb1){   // one 64-k-tile
      const unsigned short* asb = &As[ib][0];
      #pragma unroll
      for (int kk = 0; kk < 2; ++kk){
        const int g8 = ((kk * 4 + hq) ^ sw) << 3;
        bf16x8 pb = kk ? pb1 : pb0;
        #pragma unroll
        for (int mi = 0; mi < 4; ++mi){
          bf16x8 af = *(const bf16x8*)&asb[(mi * 16 + r0) * 64 + g8];
          acc[mi][0] = __builtin_amdgcn_mfma_f32_16x16x32_bf16(af, pb, acc[mi][0], 0, 0, 0);
        }
      }
    };
    // SS(S): stage tiles 2S+4,2S+5; load B tiles 2S+2,2S+3; wait; barrier; compute 2S,2S+1.
    // Buffer (2S+4)&7 was last read at CMPT(S-2), separated by barrier(S-1): safe.
    #define SS(S, BC, BN, N) do{ \
      if (2*(S)+4 < 64){ stageA((2*(S)+4)&7, 2*(S)+4); stageA((2*(S)+5)&7, 2*(S)+5); } \
      if (2*(S)+2 < 64){ LDBX(BN, 2*(S)+2); } \
      VMW(N); BARX; \
      CMPT((2*(S))&7, BC[0], BC[1]); \
      CMPT((2*(S)+1)&7, BC[2], BC[3]); \
      asm volatile("" ::: "memory"); \
    }while(0)

    stageA(0, 0); stageA(1, 1); stageA(2, 2); stageA(3, 3);   // tiles 0..3 (8 ops)
    LDBX(bA, 0);                                              // B tiles 0,1 (4 ops)
    SS(0, bA, bB, 8);
    #pragma unroll 1
    for (int S = 1; S < 29; S += 2){
      SS(S,     bB, bA, 8);
      SS(S + 1, bA, bB, 8);
    }
    SS(29, bB, bA, 8);
    SS(30, bA, bB, 4);
    SS(31, bB, bA, 0);
    #undef SS
  } else {
    // ---- R12-proven per-tile pipeline (4-deep, stage distance 2) ----
    bf16x8 b0[2][2], b1[2][2];
    #define LDB2(PB, T) do{ \
      PB[0][0] = *(const bf16x8*)(Bb0 + (size_t)(T) * 1024); \
      PB[0][1] = *(const bf16x8*)(Bb0 + (size_t)(T) * 1024 + 512); \
      PB[1][0] = *(const bf16x8*)(Bb1 + (size_t)(T) * 1024); \
      PB[1][1] = *(const bf16x8*)(Bb1 + (size_t)(T) * 1024 + 512); }while(0)
    #define CMP128(IB, PB) do{ \
      const unsigned short* asb = &As[(IB)][0]; \
      _Pragma("unroll") for (int kk = 0; kk < 2; ++kk){ \
        const int g8 = ((kk * 4 + hq) ^ sw) << 3; \
        _Pragma("unroll") for (int mi = 0; mi < 4; ++mi){ \
          bf16x8 af = *(const bf16x8*)&asb[(mi * 16 + r0) * 64 + g8]; \
          acc[mi][0] = __builtin_amdgcn_mfma_f32_16x16x32_bf16(af, PB[0][kk], acc[mi][0], 0, 0, 0); \
          acc[mi][1] = __builtin_amdgcn_mfma_f32_16x16x32_bf16(af, PB[1][kk], acc[mi][1], 0, 0, 0); \
        } } }while(0)
    #define SUB128(T, BC, BL, N) do{ \
      if ((T) + 1 < 64) LDB2(BL, (T) + 1); \
      if ((T) + 2 < 64) stageA(((T) + 2) & 3, (T) + 2); \
      VMW(N); BARX; CMP128((T) & 3, BC); asm volatile("" ::: "memory"); }while(0)

    stageA(0, 0); stageA(1, 1);
    LDB2(b0, 0);
    SUB128(0, b0, b1, 6);
    #pragma unroll 1
    for (int T0 = 1; T0 <= 59; T0 += 2){
      SUB128(T0 + 0, b1, b0, 8);
      SUB128(T0 + 1, b0, b1, 8);
    }
    SUB128(61, b1, b0, 8);
    SUB128(62, b0, b1, 6);
    SUB128(63, b1, b0, 0);
    #undef SUB128
    #undef CMP128
    #undef LDB2
  }

  // ---- fused epilogue: C/D layout col = lane&15 (r0), row = hq*4 + j ----
  const bool isScat = (NC == 64) || (w >= 2);
  if (isScat){
    const int wS = (NC == 64) ? w : (w - 2);
    #pragma unroll
    for (int mi = 0; mi < 4; ++mi){
      const int rb = m0 + mi * 16 + hq * 4;
      const size_t rowb = (size_t)b * NN + rb;
      float4 dv4 = *(const float4*)(dinv + (size_t)b * NN + rb);
      #pragma unroll
      for (int ni = 0; ni < NF; ++ni){
        const int cs = wS * 16 * NF + ni * 16 + r0;   // local scat col 0..63
        float pn[4];
        #pragma unroll
        for (int j = 0; j < 4; ++j){
          float pv = sprev[(rowb + j) * 64 + cs];
          pn[j] = 0.5f * (pv + acc[mi][ni][j]);
          P[(rowb + j) * 64 + cs] = pn[j];
        }
        if (snap){
          #pragma unroll
          for (int j = 0; j < 4; ++j) snap[(rowb + j) * 64 + cs] = pn[j];
        }
        if (writeVtS){
          const int ct = 4 + wS * NF + ni;
          const int tp = rb >> 6, kkp = (rb >> 5) & 1;
          const int lp = r0 + 16 * ((rb >> 3) & 3), hf = (rb >> 2) & 1;
          ushort4 vv = make_ushort4(f2bf(dv4.x * pn[0]), f2bf(dv4.y * pn[1]),
                                    f2bf(dv4.z * pn[2]), f2bf(dv4.w * pn[3]));
          *(ushort4*)(BtW + ((((size_t)b * 8 + ct) * 64 + tp) * 2 + kkp) * 512
                          + (lp << 3) + hf * 4) = vv;
        }
      }
    }
  }
  if constexpr (NC == 128){
    if (!isScat){                                     // gcn waves 0,1
      #pragma unroll
      for (int mi = 0; mi < 4; ++mi){
        const int rb = m0 + mi * 16 + hq * 4;
        const size_t rowb = (size_t)b * NN + rb;
        float4 dq4 = *(const float4*)(dsq + (size_t)b * NN + rb);
        #pragma unroll
        for (int ni = 0; ni < NF; ++ni){
          const int cg = w * 16 * NF + ni * 16 + r0;  // gcn col 0..63
          float hn[4];
          const float dq[4] = {dq4.x, dq4.y, dq4.z, dq4.w};
          #pragma unroll
          for (int j = 0; j < 4; ++j){
            float hv = gprev[(rowb + j) * 64 + cg];
            hn[j] = (acc[mi][ni][j] + dq[j] * hv) * dq[j];
            gout[(rowb + j) * 64 + cg] = hn[j];
          }
          if (writeVtG){
            const int ct = w * NF + ni;
            const int tp = rb >> 6, kkp = (rb >> 5) & 1;
            const int lp = r0 + 16 * ((rb >> 3) & 3), hf = (rb >> 2) & 1;
            ushort4 vv = make_ushort4(f2bf(dq[0] * hn[0]), f2bf(dq[1] * hn[1]),
                                      f2bf(dq[2] * hn[2]), f2bf(dq[3] * hn[3]));
            *(ushort4*)(BtW + ((((size_t)b * 8 + ct) * 64 + tp) * 2 + kkp) * 512
                            + (lp << 3) + hf * 4) = vv;
          }
        }
      }
    }
  }
}

// ---------------- attention over 6 branches + 2-layer MLP ----------------
__global__ __launch_bounds__(256) void k_attn(
    const float* __restrict__ X,  const float* __restrict__ hA, const float* __restrict__ hA2,
    const float* __restrict__ U1, const float* __restrict__ U2, const float* __restrict__ U4,
    const float* __restrict__ U8, const float* __restrict__ W1, const float* __restrict__ b1,
    const float* __restrict__ W2, const float* __restrict__ b2, const float* __restrict__ av,
    const int* __restrict__ momp, float* __restrict__ out)
{
  __shared__ float W1s[64][65], W2s[64][65];
  __shared__ float a1s[64], a2s[64], b1s[64], b2s[64];
  __shared__ float hp[4][64], o1[4][64];
  const int tid = threadIdx.x;
  for (int e = tid; e < 4096; e += 256){
    W1s[e >> 6][e & 63] = W1[e];
    W2s[e >> 6][e & 63] = W2[e];
  }
  if (tid < 64){ a1s[tid] = av[tid]; a2s[tid] = av[64 + tid]; b1s[tid] = b1[tid]; b2s[tid] = b2[tid]; }
  __syncthreads();
  const int w = tid >> 6, l = tid & 63;
  size_t row = (size_t)blockIdx.x * 4 + w;
  size_t off = row * 64 + l;
  float x  = X[off];
  float u1 = U1[off], u2 = U2[off], u4 = U4[off], u8 = U8[off];
  float br[6];
  br[0] = leaky01(hA[off]);
  br[1] = leaky01(hA2[off]);
  float d1 = fabsf(x - u1), d2 = fabsf(u1 - u2), d3 = fabsf(u2 - u4), d4 = fabsf(u4 - u8);
  int mom = *momp;
  if (mom == 1){ br[2] = d1; br[3] = d2; br[4] = d3; br[5] = d4; }
  else {
    float m = (float)mom;
    br[2] = powf(d1, m); br[3] = powf(d2, m); br[4] = powf(d3, m); br[5] = powf(d4, m);
  }
  float v = fmaxf(x, 0.f) * a1s[l];
  for (int o = 32; o; o >>= 1) v += __shfl_xor(v, o);
  float base = v;
  float e[6];
  #pragma unroll
  for (int k = 0; k < 6; ++k){
    float t = fmaxf(br[k], 0.f) * a2s[l];
    for (int o = 32; o; o >>= 1) t += __shfl_xor(t, o);
    e[k] = base + t;
  }
  float mx = e[0];
  #pragma unroll
  for (int k = 1; k < 6; ++k) mx = fmaxf(mx, e[k]);
  float s = 0.f, att[6];
  #pragma unroll
  for (int k = 0; k < 6; ++k){ att[k] = expf(e[k] - mx); s += att[k]; }
  float inv = 1.0f / (6.0f * s);
  float hpv = 0.f;
  #pragma unroll
  for (int k = 0; k < 6; ++k) hpv += att[k] * br[k];
  hpv *= inv;
  hp[w][l] = hpv;
  __syncthreads();
  float acc = b1s[l];
  #pragma unroll 8
  for (int c = 0; c < 64; ++c) acc += hp[w][c] * W1s[l][c];
  o1[w][l] = leaky01(acc);
  __syncthreads();
  float acc2 = b2s[l];
  #pragma unroll 8
  for (int c = 0; c < 64; ++c) acc2 += o1[w][c] * W2s[l][c];
  out[off] = leaky01(acc2);
}

// ---------------- workspace layout ----------------
static constexpr size_t OFF_ADJB = 0;                                   // bf16 A staging image
static constexpr size_t OFF_VTA  = OFF_ADJB + (size_t)BB * NN * NN * 2; // bf16 frag-order B
static constexpr size_t OFF_VTB  = OFF_VTA  + (size_t)BB * 128 * NN * 2;
static constexpr size_t OFF_HA   = OFF_VTB  + (size_t)BB * 128 * NN * 2;
static constexpr size_t OFF_HA2  = OFF_HA   + (size_t)BB * NN * 64 * 4;
static constexpr size_t OFF_P    = OFF_HA2  + (size_t)BB * NN * 64 * 4;
static constexpr size_t OFF_U1   = OFF_P    + (size_t)BB * NN * 64 * 4;
static constexpr size_t OFF_U2   = OFF_U1   + (size_t)BB * NN * 64 * 4;
static constexpr size_t OFF_U4   = OFF_U2   + (size_t)BB * NN * 64 * 4;
static constexpr size_t OFF_U8   = OFF_U4   + (size_t)BB * NN * 64 * 4;
static constexpr size_t OFF_DINV = OFF_U8   + (size_t)BB * NN * 64 * 4;
static constexpr size_t OFF_DS   = OFF_DINV + (size_t)BB * NN * 4;
static constexpr size_t WS_NEED  = OFF_DS   + (size_t)BB * NN * 4;

extern "C" void kernel_launch(void* const* d_in, const int* in_sizes, int n_in,
                              void* d_out, int out_size, void* d_ws, size_t ws_size,
                              hipStream_t stream)
{
  const float* X   = (const float*)d_in[0];
  const float* adj = (const float*)d_in[1];
  const float* W1  = (const float*)d_in[2];
  const float* b1  = (const float*)d_in[3];
  const float* W2  = (const float*)d_in[4];
  const float* b2  = (const float*)d_in[5];
  const float* av  = (const float*)d_in[6];
  const int*  momp = (const int*)d_in[7];
  float* out = (float*)d_out;

  if (ws_size < WS_NEED){
    fprintf(stderr, "kernel_launch: workspace too small: %zu < %zu\n", ws_size, WS_NEED);
    return;
  }
  char* w = (char*)d_ws;
  unsigned short* At  = (unsigned short*)(w + OFF_ADJB);
  unsigned short* vtA = (unsigned short*)(w + OFF_VTA);
  unsigned short* vtB = (unsigned short*)(w + OFF_VTB);
  float* hA   = (float*)(w + OFF_HA);
  float* hA2  = (float*)(w + OFF_HA2);
  float* P    = (float*)(w + OFF_P);
  float* U1   = (float*)(w + OFF_U1);
  float* U2   = (float*)(w + OFF_U2);
  float* U4   = (float*)(w + OFF_U4);
  float* U8   = (float*)(w + OFF_U8);
  float* dinv = (float*)(w + OFF_DINV);
  float* dsq  = (float*)(w + OFF_DS);

  k_convert<<<512, 256, 0, stream>>>(adj, At, dinv, dsq);
  dim3 tg64(NN / 64, BB);
  k_prep<<<tg64, 256, 0, stream>>>(X, dinv, dsq, vtA);

  // pass 1: dual RHS (gcn: dsq*X -> hA, scat: dinv*X -> P,U1); writes vtB (both halves)
  k_gemm_fused<128><<<512, 256, 0, stream>>>(At, vtA, 0,
      X, P, U1, dinv, 1, X, hA, dsq, 1, vtB);
  // pass 2: dual RHS (gcn -> hA2, scat -> P,U2); writes vtA (scat half)
  k_gemm_fused<128><<<512, 256, 0, stream>>>(At, vtB, 0,
      P, P, U2, dinv, 1, hA, hA2, dsq, 0, vtA);
  // passes 3..8: scattering only, alternate vtA/vtB
  unsigned short* vr = vtA;
  unsigned short* vw = vtB;
  for (int k = 3; k <= 8; ++k){
    float* snap = (k == 4) ? U4 : nullptr;
    float* pdst = (k == 8) ? U8 : P;
    k_gemm_fused<64><<<512, 256, 0, stream>>>(At, vr, 4,
        P, pdst, snap, dinv, (k < 8) ? 1 : 0, nullptr, nullptr, nullptr, 0, vw);
    unsigned short* t = vr; vr = vw; vw = t;
  }

  k_attn<<<BB * NN / 4, 256, 0, stream>>>(X, hA, hA2, U1, U2, U4, U8,
                                          W1, b1, W2, b2, av, momp, out);
}